// Round 5
// baseline (920.074 us; speedup 1.0000x reference)
//
#include <hip/hip_runtime.h>

// TransformerConstrainedPooling on MI355X (gfx950).
// Fused: per-thread MLP+softmax+argmax (phase 1), then each S row written
// exactly once as coalesced non-temporal dwordx4 with the 5 probs inserted
// inline (phase 2, wave-per-row). cluster_ids appended at d_out + N*TC.

constexpr int kN   = 131072;
constexpr int kF   = 128;
constexpr int kH   = 64;    // F/2
constexpr int kK   = 5;
constexpr int kTC  = 1280;  // T*K  (320 float4 per row = 5 * 64 lanes)
constexpr int ROWS = 256;   // rows per block
constexpr int BLK  = 256;   // threads per block (4 waves)

// clang native vector — accepted by __builtin_nontemporal_store
typedef float f32x4 __attribute__((ext_vector_type(4)));

__global__ __launch_bounds__(BLK, 4)
void tcp_fused(const float* __restrict__ x,
               const int*   __restrict__ tids,
               const float* __restrict__ W1,
               const float* __restrict__ b1,
               const float* __restrict__ W2,
               const float* __restrict__ b2,
               float* __restrict__ out)
{
    __shared__ float p_lds[ROWS][kK];
    __shared__ int   c0_lds[ROWS];

    const int tid = threadIdx.x;
    const long long row = (long long)blockIdx.x * ROWS + tid;

    // ---------- phase 1: per-thread MLP (row in registers) ----------
    float h[kH];
#pragma unroll
    for (int j = 0; j < kH; ++j) h[j] = b1[j];

    const f32x4* x4 = reinterpret_cast<const f32x4*>(x + row * kF);
#pragma unroll 2
    for (int f4 = 0; f4 < kF / 4; ++f4) {
        const f32x4 xv = x4[f4];
#pragma unroll
        for (int e = 0; e < 4; ++e) {
            const float xs = xv[e];
            // W1 address is wave-uniform -> scalar loads, SGPR FMA operand
            const float* w = W1 + (f4 * 4 + e) * kH;
#pragma unroll
            for (int j = 0; j < kH; ++j)
                h[j] = fmaf(xs, w[j], h[j]);
        }
    }
#pragma unroll
    for (int j = 0; j < kH; ++j) h[j] = fmaxf(h[j], 0.0f);

    float lg[kK];
#pragma unroll
    for (int k = 0; k < kK; ++k) lg[k] = b2[k];
#pragma unroll 8
    for (int j = 0; j < kH; ++j) {
        const float* w = W2 + j * kK;  // wave-uniform
#pragma unroll
        for (int k = 0; k < kK; ++k)
            lg[k] = fmaf(h[j], w[k], lg[k]);
    }

    // softmax (match JAX: max-subtract, exp, divide)
    float m = lg[0];
#pragma unroll
    for (int k = 1; k < kK; ++k) m = fmaxf(m, lg[k]);
    float p[kK];
    float ssum = 0.0f;
#pragma unroll
    for (int k = 0; k < kK; ++k) { p[k] = expf(lg[k] - m); ssum += p[k]; }
#pragma unroll
    for (int k = 0; k < kK; ++k) p[k] = p[k] / ssum;

    // argmax, first-max-wins (jnp.argmax tie semantics)
    int am = 0; float best = p[0];
#pragma unroll
    for (int k = 1; k < kK; ++k) if (p[k] > best) { best = p[k]; am = k; }

    const int c0 = tids[row] * kK;
    c0_lds[tid] = c0;
#pragma unroll
    for (int k = 0; k < kK; ++k) p_lds[tid][k] = p[k];

    // cluster_ids live after S, as the output dtype (float)
    out[(long long)kN * kTC + row] = (float)(c0 + am);

    __syncthreads();

    // ---------- phase 2: wave-per-row, dense coalesced non-temporal ----------
    const int wave = tid >> 6;   // 0..3
    const int lane = tid & 63;
    float* bbase = out + (long long)blockIdx.x * ROWS * kTC;
    for (int r = wave; r < ROWS; r += 4) {
        f32x4* orow = reinterpret_cast<f32x4*>(bbase + (long long)r * kTC);
        const int c0r = c0_lds[r];           // wave-uniform -> scalar
#pragma unroll
        for (int s = 0; s < kK; ++s) {       // 5 * 64 lanes = 320 f32x4 = row
            const int i = lane + s * 64;     // f32x4 index in row
            f32x4 v = {0.f, 0.f, 0.f, 0.f};
            const int d0 = i * 4 - c0r;      // col - c0 for element 0
            if (d0 >= -3 && d0 <= 4) {       // f32x4 overlaps [c0, c0+5)
#pragma unroll
                for (int e = 0; e < 4; ++e) {
                    const int d = d0 + e;
                    if ((unsigned)d < (unsigned)kK) v[e] = p_lds[r][d];
                }
            }
            __builtin_nontemporal_store(v, orow + i);
        }
    }
}

extern "C" void kernel_launch(void* const* d_in, const int* in_sizes, int n_in,
                              void* d_out, int out_size, void* d_ws, size_t ws_size,
                              hipStream_t stream) {
    const float* x  = (const float*)d_in[0];
    const int* tids = (const int*)d_in[1];
    const float* W1 = (const float*)d_in[2];
    const float* b1 = (const float*)d_in[3];
    const float* W2 = (const float*)d_in[4];
    const float* b2 = (const float*)d_in[5];
    float* out = (float*)d_out;

    dim3 grid(kN / ROWS);   // 512 blocks
    dim3 block(BLK);        // 256 threads
    hipLaunchKernelGGL(tcp_fused, grid, block, 0, stream,
                       x, tids, W1, b1, W2, b2, out);
}

// Round 9
// 915.315 us; speedup vs baseline: 1.0052x; 1.0052x over previous
//
#include <hip/hip_runtime.h>

// TransformerConstrainedPooling on MI355X (gfx950). Two-kernel split:
//  A: per-thread MLP+softmax+argmax -> p[5],c0 into d_ws (32B/row),
//     cluster_ids into d_out tail.
//  B: fill-like streaming writer of S (plain dwordx4, 1KB/wave-instr),
//     probs inserted from an 8KB LDS table.
// Rationale: harness's own fillBufferAligned hits 6.36 TB/s (79% peak) on
// this very buffer with tiny-VGPR plain stores; mirror it.

constexpr int kN   = 131072;
constexpr int kF   = 128;
constexpr int kH   = 64;    // F/2
constexpr int kK   = 5;
constexpr int kTC  = 1280;  // T*K ; 320 f32x4 per row = 5 * 64 lanes
constexpr int ROWS = 256;   // rows per block
constexpr int BLK  = 256;   // threads per block (4 waves)
constexpr int INFO = 8;     // floats per row in ws: p0..p4, c0, pad, pad

typedef float f32x4 __attribute__((ext_vector_type(4)));

// ---------------- Kernel A: compute ----------------
__global__ __launch_bounds__(BLK, 2)
void tcp_compute(const float* __restrict__ x,
                 const int*   __restrict__ tids,
                 const float* __restrict__ W1,
                 const float* __restrict__ b1,
                 const float* __restrict__ W2,
                 const float* __restrict__ b2,
                 float* __restrict__ info,
                 float* __restrict__ out)
{
    const int tid = threadIdx.x;
    const long long row = (long long)blockIdx.x * ROWS + tid;

    float h[kH];
#pragma unroll
    for (int j = 0; j < kH; ++j) h[j] = b1[j];

    const f32x4* x4 = reinterpret_cast<const f32x4*>(x + row * kF);
#pragma unroll 2
    for (int f4 = 0; f4 < kF / 4; ++f4) {
        const f32x4 xv = x4[f4];
#pragma unroll
        for (int e = 0; e < 4; ++e) {
            const float xs = xv[e];
            const float* w = W1 + (f4 * 4 + e) * kH;  // wave-uniform -> s_load
#pragma unroll
            for (int j = 0; j < kH; ++j)
                h[j] = fmaf(xs, w[j], h[j]);
        }
    }
#pragma unroll
    for (int j = 0; j < kH; ++j) h[j] = fmaxf(h[j], 0.0f);

    float lg[kK];
#pragma unroll
    for (int k = 0; k < kK; ++k) lg[k] = b2[k];
#pragma unroll 8
    for (int j = 0; j < kH; ++j) {
        const float* w = W2 + j * kK;  // wave-uniform
#pragma unroll
        for (int k = 0; k < kK; ++k)
            lg[k] = fmaf(h[j], w[k], lg[k]);
    }

    // softmax (match JAX: max-subtract, exp, divide)
    float m = lg[0];
#pragma unroll
    for (int k = 1; k < kK; ++k) m = fmaxf(m, lg[k]);
    float p[kK];
    float ssum = 0.0f;
#pragma unroll
    for (int k = 0; k < kK; ++k) { p[k] = expf(lg[k] - m); ssum += p[k]; }
#pragma unroll
    for (int k = 0; k < kK; ++k) p[k] = p[k] / ssum;

    // argmax, first-max-wins (jnp.argmax tie semantics)
    int am = 0; float best = p[0];
#pragma unroll
    for (int k = 1; k < kK; ++k) if (p[k] > best) { best = p[k]; am = k; }

    const int c0 = tids[row] * kK;

    f32x4 lo = {p[0], p[1], p[2], p[3]};
    f32x4 hi = {p[4], (float)c0, 0.0f, 0.0f};   // c0 <= 1275, exact in float
    f32x4* irow = reinterpret_cast<f32x4*>(info + row * INFO);
    irow[0] = lo;
    irow[1] = hi;

    // cluster_ids live after S, as the output dtype (float)
    out[(long long)kN * kTC + row] = (float)(c0 + am);
}

// ---------------- Kernel B: fill-like writer ----------------
__global__ __launch_bounds__(BLK)
void tcp_write(const float* __restrict__ info,
               float* __restrict__ out)
{
    __shared__ float ld[ROWS][INFO];   // 8 KB

    const int tid = threadIdx.x;
    const long long base = (long long)blockIdx.x * ROWS;

    // cooperative coalesced load of this block's 256 row-infos (512 f32x4)
    const f32x4* isrc = reinterpret_cast<const f32x4*>(info + base * INFO);
    f32x4* ldst = reinterpret_cast<f32x4*>(&ld[0][0]);
#pragma unroll
    for (int q = 0; q < 2; ++q)
        ldst[tid + q * BLK] = isrc[tid + q * BLK];
    __syncthreads();

    const int wave = tid >> 6;
    const int lane = tid & 63;
    float* bbase = out + base * kTC;
    for (int r = wave; r < ROWS; r += 4) {
        f32x4* orow = reinterpret_cast<f32x4*>(bbase + (long long)r * kTC);
        const int c0r = (int)ld[r][kK];          // wave-uniform
#pragma unroll
        for (int s = 0; s < kK; ++s) {           // 5 * 64 lanes = full row
            const int i = lane + s * 64;
            f32x4 v = {0.f, 0.f, 0.f, 0.f};
            const int d0 = i * 4 - c0r;
            if (d0 >= -3 && d0 <= 4) {           // overlaps [c0, c0+5)
#pragma unroll
                for (int e = 0; e < 4; ++e) {
                    const int d = d0 + e;
                    if ((unsigned)d < (unsigned)kK) v[e] = ld[r][d];
                }
            }
            orow[i] = v;                          // plain store (like the fill)
        }
    }
}

extern "C" void kernel_launch(void* const* d_in, const int* in_sizes, int n_in,
                              void* d_out, int out_size, void* d_ws, size_t ws_size,
                              hipStream_t stream) {
    const float* x  = (const float*)d_in[0];
    const int* tids = (const int*)d_in[1];
    const float* W1 = (const float*)d_in[2];
    const float* b1 = (const float*)d_in[3];
    const float* W2 = (const float*)d_in[4];
    const float* b2 = (const float*)d_in[5];
    float* out  = (float*)d_out;
    float* info = (float*)d_ws;    // N*8 floats = 4 MB

    dim3 grid(kN / ROWS);   // 512 blocks
    dim3 block(BLK);
    hipLaunchKernelGGL(tcp_compute, grid, block, 0, stream,
                       x, tids, W1, b1, W2, b2, info, out);
    hipLaunchKernelGGL(tcp_write, grid, block, 0, stream,
                       info, out);
}

// Round 14
// 913.169 us; speedup vs baseline: 1.0076x; 1.0024x over previous
//
#include <hip/hip_runtime.h>

// TransformerConstrainedPooling on MI355X (gfx950).
// S is 99.7% zeros: zero it with hipMemsetAsync (dispatches the runtime's
// fillBufferAligned, measured 6.26-6.36 TB/s on this device), then one
// compute kernel scatters only the 5 probs per row + cluster_ids.
// Phase-1 MLP numerics byte-identical to the R5/R9 validated versions.

constexpr int kN   = 131072;
constexpr int kF   = 128;
constexpr int kH   = 64;    // F/2
constexpr int kK   = 5;
constexpr int kTC  = 1280;  // T*K
constexpr int ROWS = 256;   // rows per block
constexpr int BLK  = 256;   // threads per block

typedef float f32x4 __attribute__((ext_vector_type(4)));

__global__ __launch_bounds__(BLK, 2)
void tcp_compute(const float* __restrict__ x,
                 const int*   __restrict__ tids,
                 const float* __restrict__ W1,
                 const float* __restrict__ b1,
                 const float* __restrict__ W2,
                 const float* __restrict__ b2,
                 float* __restrict__ out)
{
    const int tid = threadIdx.x;
    const long long row = (long long)blockIdx.x * ROWS + tid;

    // ---------- per-thread MLP (row in registers) ----------
    float h[kH];
#pragma unroll
    for (int j = 0; j < kH; ++j) h[j] = b1[j];

    const f32x4* x4 = reinterpret_cast<const f32x4*>(x + row * kF);
#pragma unroll 2
    for (int f4 = 0; f4 < kF / 4; ++f4) {
        const f32x4 xv = x4[f4];
#pragma unroll
        for (int e = 0; e < 4; ++e) {
            const float xs = xv[e];
            const float* w = W1 + (f4 * 4 + e) * kH;  // wave-uniform -> s_load
#pragma unroll
            for (int j = 0; j < kH; ++j)
                h[j] = fmaf(xs, w[j], h[j]);
        }
    }
#pragma unroll
    for (int j = 0; j < kH; ++j) h[j] = fmaxf(h[j], 0.0f);

    float lg[kK];
#pragma unroll
    for (int k = 0; k < kK; ++k) lg[k] = b2[k];
#pragma unroll 8
    for (int j = 0; j < kH; ++j) {
        const float* w = W2 + j * kK;  // wave-uniform
#pragma unroll
        for (int k = 0; k < kK; ++k)
            lg[k] = fmaf(h[j], w[k], lg[k]);
    }

    // softmax (match JAX: max-subtract, exp, divide)
    float m = lg[0];
#pragma unroll
    for (int k = 1; k < kK; ++k) m = fmaxf(m, lg[k]);
    float p[kK];
    float ssum = 0.0f;
#pragma unroll
    for (int k = 0; k < kK; ++k) { p[k] = expf(lg[k] - m); ssum += p[k]; }
#pragma unroll
    for (int k = 0; k < kK; ++k) p[k] = p[k] / ssum;

    // argmax, first-max-wins (jnp.argmax tie semantics)
    int am = 0; float best = p[0];
#pragma unroll
    for (int k = 1; k < kK; ++k) if (p[k] > best) { best = p[k]; am = k; }

    const int c0 = tids[row] * kK;

    // scatter the 5 probs into the pre-zeroed S row (20 B, 1-2 cache lines)
    float* srow = out + row * (long long)kTC + c0;
#pragma unroll
    for (int k = 0; k < kK; ++k) srow[k] = p[k];

    // cluster_ids live after S, as the output dtype (float)
    out[(long long)kN * kTC + row] = (float)(c0 + am);
}

extern "C" void kernel_launch(void* const* d_in, const int* in_sizes, int n_in,
                              void* d_out, int out_size, void* d_ws, size_t ws_size,
                              hipStream_t stream) {
    const float* x  = (const float*)d_in[0];
    const int* tids = (const int*)d_in[1];
    const float* W1 = (const float*)d_in[2];
    const float* b1 = (const float*)d_in[3];
    const float* W2 = (const float*)d_in[4];
    const float* b2 = (const float*)d_in[5];
    float* out = (float*)d_out;

    // Zero the S block via the runtime's fill path (proven 6.26+ TB/s here).
    // Capturable: becomes a memset node in the graph.
    hipMemsetAsync(d_out, 0, (size_t)kN * kTC * sizeof(float), stream);

    dim3 grid(kN / ROWS);   // 512 blocks
    dim3 block(BLK);
    hipLaunchKernelGGL(tcp_compute, grid, block, 0, stream,
                       x, tids, W1, b1, W2, b2, out);
}

// Round 17
// 750.919 us; speedup vs baseline: 1.2253x; 1.2161x over previous
//
#include <hip/hip_runtime.h>

// TransformerConstrainedPooling on MI355X (gfx950), v2.
// hipMemsetAsync zeroes S (runtime fill measured 6.26-6.36 TB/s here).
// One fused kernel: LDS-tiled register-blocked GEMM for h = relu(x@W1+b1)
// (replaces the per-thread GEMV that was ~19x over the FMA floor), then the
// R5/R9/R14-validated epilogue (logits/softmax/argmax/scatter), 1 row/thread.

constexpr int kN   = 131072;
constexpr int kF   = 128;
constexpr int kH   = 64;    // F/2
constexpr int kK   = 5;
constexpr int kTC  = 1280;  // T*K
constexpr int ROWS = 256;   // rows per block
constexpr int BLK  = 512;   // threads per block (8 waves)

typedef float f32x4 __attribute__((ext_vector_type(4)));

// LDS: buf = union{ xt[64][257] (65792 f) ; hbuf[256][68] (17408 f) }
//      W1s[128][64], W2s[64][8] (pad 5->8), b2s
__global__ __launch_bounds__(BLK)
void tcp_fused(const float* __restrict__ x,
               const int*   __restrict__ tids,
               const float* __restrict__ W1,
               const float* __restrict__ b1,
               const float* __restrict__ W2,
               const float* __restrict__ b2,
               float* __restrict__ out)
{
    __shared__ float buf[17408];     // 69632 B (max of xt/hbuf uses)
    __shared__ float W1s[128 * 64];  // 32 KB
    __shared__ float W2s[64 * 8];    // 2 KB
    __shared__ float b2s[8];

    const int tid = threadIdx.x;
    const int i   = tid & 31;   // row-group lane: rows i+32k, k=0..7
    const int jj  = tid >> 5;   // col group 0..15: cols 4jj..4jj+3
    const long long brow = (long long)blockIdx.x * ROWS;

    // ---- stage W1 (linear, coalesced b128), W2 (padded), b2 ----
    {
        const f32x4* g = reinterpret_cast<const f32x4*>(W1);
        f32x4* s = reinterpret_cast<f32x4*>(W1s);
#pragma unroll
        for (int q = 0; q < 4; ++q) s[tid + q * BLK] = g[tid + q * BLK];
    }
    if (tid < 320) W2s[(tid / 5) * 8 + (tid % 5)] = W2[tid];
    if (tid < 5)   b2s[tid] = b2[tid];

    // acc init = b1 (same summation order as validated kernel: b1 first)
    float bv[4];
#pragma unroll
    for (int c = 0; c < 4; ++c) bv[c] = b1[jj * 4 + c];   // wave-uniform
    float acc[8][4];
#pragma unroll
    for (int k = 0; k < 8; ++k)
#pragma unroll
        for (int c = 0; c < 4; ++c) acc[k][c] = bv[c];

    const f32x4* x4g = reinterpret_cast<const f32x4*>(x);

    for (int half = 0; half < 2; ++half) {
        __syncthreads();  // buf free (and W1s staged, on first pass)
        // stage xt[64][257] for f-half: coalesced read, transposed write
#pragma unroll
        for (int q = 0; q < 8; ++q) {
            const int idx = q * BLK + tid;   // 0..4095 = 256 rows x 16 f4
            const int row = idx >> 4;
            const int f4  = idx & 15;
            const f32x4 v = x4g[(brow + row) * 32 + half * 16 + f4];
#pragma unroll
            for (int e = 0; e < 4; ++e)
                buf[(f4 * 4 + e) * 257 + row] = v[e];
        }
        __syncthreads();
        // 64 f-steps: 8 conflict-free b32 (x) + 1 broadcast b128 (W1) + 32 FMA
        for (int fh = 0; fh < 64; ++fh) {
            const f32x4 wv =
                *reinterpret_cast<const f32x4*>(&W1s[(half * 64 + fh) * 64 + jj * 4]);
            float xv[8];
#pragma unroll
            for (int k = 0; k < 8; ++k) xv[k] = buf[fh * 257 + i + 32 * k];
#pragma unroll
            for (int k = 0; k < 8; ++k)
#pragma unroll
                for (int c = 0; c < 4; ++c)
                    acc[k][c] = fmaf(xv[k], wv[c], acc[k][c]);
        }
    }

    __syncthreads();  // xt reads done; reuse buf as hbuf[256][68]
#pragma unroll
    for (int k = 0; k < 8; ++k) {
        f32x4 hv;
#pragma unroll
        for (int c = 0; c < 4; ++c) hv[c] = fmaxf(acc[k][c], 0.0f);
        *reinterpret_cast<f32x4*>(&buf[(i + 32 * k) * 68 + jj * 4]) = hv;
    }
    __syncthreads();

    // ---- validated epilogue, 1 row/thread (waves 4-7 idle, no barriers) ----
    if (tid < ROWS) {
        const int row = tid;
        const long long grow = brow + row;
        float hr[64];
#pragma unroll
        for (int c4 = 0; c4 < 16; ++c4) {
            const f32x4 v = *reinterpret_cast<const f32x4*>(&buf[row * 68 + c4 * 4]);
#pragma unroll
            for (int e = 0; e < 4; ++e) hr[c4 * 4 + e] = v[e];
        }
        f32x4 lgv = {b2s[0], b2s[1], b2s[2], b2s[3]};
        float lg4 = b2s[4];
#pragma unroll 8
        for (int j = 0; j < 64; ++j) {
            const float hj = hr[j];
            const f32x4 wv = *reinterpret_cast<const f32x4*>(&W2s[j * 8]);
#pragma unroll
            for (int c = 0; c < 4; ++c) lgv[c] = fmaf(hj, wv[c], lgv[c]);
            lg4 = fmaf(hj, W2s[j * 8 + 4], lg4);
        }
        float lg[kK] = {lgv[0], lgv[1], lgv[2], lgv[3], lg4};
        float m = lg[0];
#pragma unroll
        for (int k = 1; k < kK; ++k) m = fmaxf(m, lg[k]);
        float p[kK]; float ssum = 0.0f;
#pragma unroll
        for (int k = 0; k < kK; ++k) { p[k] = expf(lg[k] - m); ssum += p[k]; }
#pragma unroll
        for (int k = 0; k < kK; ++k) p[k] = p[k] / ssum;
        int am = 0; float best = p[0];
#pragma unroll
        for (int k = 1; k < kK; ++k) if (p[k] > best) { best = p[k]; am = k; }

        const int c0 = tids[grow] * kK;
        float* srow = out + grow * (long long)kTC + c0;
#pragma unroll
        for (int k = 0; k < kK; ++k) srow[k] = p[k];
        out[(long long)kN * kTC + grow] = (float)(c0 + am);
    }
}

extern "C" void kernel_launch(void* const* d_in, const int* in_sizes, int n_in,
                              void* d_out, int out_size, void* d_ws, size_t ws_size,
                              hipStream_t stream) {
    const float* x  = (const float*)d_in[0];
    const int* tids = (const int*)d_in[1];
    const float* W1 = (const float*)d_in[2];
    const float* b1 = (const float*)d_in[3];
    const float* W2 = (const float*)d_in[4];
    const float* b2 = (const float*)d_in[5];
    float* out = (float*)d_out;

    // Zero S via the runtime fill path (proven 6.26+ TB/s on this buffer).
    hipMemsetAsync(d_out, 0, (size_t)kN * kTC * sizeof(float), stream);

    dim3 grid(kN / ROWS);   // 512 blocks
    dim3 block(BLK);        // 512 threads
    hipLaunchKernelGGL(tcp_fused, grid, block, 0, stream,
                       x, tids, W1, b1, W2, b2, out);
}

// Round 18
// 742.542 us; speedup vs baseline: 1.2391x; 1.0113x over previous
//
#include <hip/hip_runtime.h>

// TransformerConstrainedPooling on MI355X (gfx950), v3.
// Single fused kernel: LDS-tiled register-blocked GEMM for h (v2, verified),
// epilogue -> p[5]/c0 into LDS, then R9-proven wave-per-row dense writer
// emits every S row once (plain f32x4, 1KB/wave-instr). No memset.

constexpr int kN   = 131072;
constexpr int kF   = 128;
constexpr int kH   = 64;    // F/2
constexpr int kK   = 5;
constexpr int kTC  = 1280;  // T*K ; 320 f32x4 per row
constexpr int ROWS = 256;   // rows per block
constexpr int BLK  = 512;   // threads per block (8 waves)

typedef float f32x4 __attribute__((ext_vector_type(4)));

__global__ __launch_bounds__(BLK)
void tcp_fused(const float* __restrict__ x,
               const int*   __restrict__ tids,
               const float* __restrict__ W1,
               const float* __restrict__ b1,
               const float* __restrict__ W2,
               const float* __restrict__ b2,
               float* __restrict__ out)
{
    __shared__ float buf[17408];     // union: xt[64][257] / hbuf[256][68]
    __shared__ float W1s[128 * 64];  // 32 KB; reused as pl[256][8] post-GEMM
    __shared__ float W2s[64 * 8];    // 2 KB (pad 5->8)
    __shared__ float b2s[8];

    const int tid = threadIdx.x;
    const int i   = tid & 31;   // row-group lane: rows i+32k
    const int jj  = tid >> 5;   // col group 0..15: cols 4jj..4jj+3
    const long long brow = (long long)blockIdx.x * ROWS;

    // ---- stage W1 (coalesced b128), W2 (padded), b2 ----
    {
        const f32x4* g = reinterpret_cast<const f32x4*>(W1);
        f32x4* s = reinterpret_cast<f32x4*>(W1s);
#pragma unroll
        for (int q = 0; q < 4; ++q) s[tid + q * BLK] = g[tid + q * BLK];
    }
    if (tid < 320) W2s[(tid / 5) * 8 + (tid % 5)] = W2[tid];
    if (tid < 5)   b2s[tid] = b2[tid];

    // acc init = b1 (b1-first summation order, validated)
    float bv[4];
#pragma unroll
    for (int c = 0; c < 4; ++c) bv[c] = b1[jj * 4 + c];
    float acc[8][4];
#pragma unroll
    for (int k = 0; k < 8; ++k)
#pragma unroll
        for (int c = 0; c < 4; ++c) acc[k][c] = bv[c];

    const f32x4* x4g = reinterpret_cast<const f32x4*>(x);

    for (int half = 0; half < 2; ++half) {
        __syncthreads();
        // stage xt[64][257]: coalesced read, transposed write
#pragma unroll
        for (int q = 0; q < 8; ++q) {
            const int idx = q * BLK + tid;
            const int row = idx >> 4;
            const int f4  = idx & 15;
            const f32x4 v = x4g[(brow + row) * 32 + half * 16 + f4];
#pragma unroll
            for (int e = 0; e < 4; ++e)
                buf[(f4 * 4 + e) * 257 + row] = v[e];
        }
        __syncthreads();
        for (int fh = 0; fh < 64; ++fh) {
            const f32x4 wv =
                *reinterpret_cast<const f32x4*>(&W1s[(half * 64 + fh) * 64 + jj * 4]);
            float xv[8];
#pragma unroll
            for (int k = 0; k < 8; ++k) xv[k] = buf[fh * 257 + i + 32 * k];
#pragma unroll
            for (int k = 0; k < 8; ++k)
#pragma unroll
                for (int c = 0; c < 4; ++c)
                    acc[k][c] = fmaf(xv[k], wv[c], acc[k][c]);
        }
    }

    __syncthreads();  // xt reads done; reuse buf as hbuf[256][68]
#pragma unroll
    for (int k = 0; k < 8; ++k) {
        f32x4 hv;
#pragma unroll
        for (int c = 0; c < 4; ++c) hv[c] = fmaxf(acc[k][c], 0.0f);
        *reinterpret_cast<f32x4*>(&buf[(i + 32 * k) * 68 + jj * 4]) = hv;
    }
    __syncthreads();  // hbuf ready; W1s (GEMM reads done) now free -> pl[256][8]

    float* pl = W1s;

    // ---- validated epilogue, 1 row/thread -> pl + cluster_ids ----
    if (tid < ROWS) {
        const int row = tid;
        const long long grow = brow + row;
        float hr[64];
#pragma unroll
        for (int c4 = 0; c4 < 16; ++c4) {
            const f32x4 v = *reinterpret_cast<const f32x4*>(&buf[row * 68 + c4 * 4]);
#pragma unroll
            for (int e = 0; e < 4; ++e) hr[c4 * 4 + e] = v[e];
        }
        f32x4 lgv = {b2s[0], b2s[1], b2s[2], b2s[3]};
        float lg4 = b2s[4];
#pragma unroll 8
        for (int j = 0; j < 64; ++j) {
            const float hj = hr[j];
            const f32x4 wv = *reinterpret_cast<const f32x4*>(&W2s[j * 8]);
#pragma unroll
            for (int c = 0; c < 4; ++c) lgv[c] = fmaf(hj, wv[c], lgv[c]);
            lg4 = fmaf(hj, W2s[j * 8 + 4], lg4);
        }
        float lg[kK] = {lgv[0], lgv[1], lgv[2], lgv[3], lg4};
        float m = lg[0];
#pragma unroll
        for (int k = 1; k < kK; ++k) m = fmaxf(m, lg[k]);
        float p[kK]; float ssum = 0.0f;
#pragma unroll
        for (int k = 0; k < kK; ++k) { p[k] = expf(lg[k] - m); ssum += p[k]; }
#pragma unroll
        for (int k = 0; k < kK; ++k) p[k] = p[k] / ssum;
        int am = 0; float best = p[0];
#pragma unroll
        for (int k = 1; k < kK; ++k) if (p[k] > best) { best = p[k]; am = k; }

        const int c0 = tids[grow] * kK;
#pragma unroll
        for (int k = 0; k < kK; ++k) pl[row * 8 + k] = p[k];
        pl[row * 8 + kK] = (float)c0;                    // exact (<= 1275)
        out[(long long)kN * kTC + grow] = (float)(c0 + am);
    }
    __syncthreads();

    // ---- R9-proven dense writer: wave-per-row, 5 f32x4 per lane ----
    const int wave = tid >> 6;   // 0..7
    const int lane = tid & 63;
    float* bbase = out + brow * kTC;
    for (int r = wave; r < ROWS; r += 8) {
        f32x4* orow = reinterpret_cast<f32x4*>(bbase + (long long)r * kTC);
        const int c0r = (int)pl[r * 8 + kK];   // wave-uniform
#pragma unroll
        for (int s = 0; s < kK; ++s) {         // 5 * 64 lanes = 320 f32x4 = row
            const int idx = lane + s * 64;
            f32x4 v = {0.f, 0.f, 0.f, 0.f};
            const int d0 = idx * 4 - c0r;
            if (d0 >= -3 && d0 <= 4) {         // overlaps [c0, c0+5)
#pragma unroll
                for (int e = 0; e < 4; ++e) {
                    const int d = d0 + e;
                    if ((unsigned)d < (unsigned)kK) v[e] = pl[r * 8 + d];
                }
            }
            orow[idx] = v;
        }
    }
}

extern "C" void kernel_launch(void* const* d_in, const int* in_sizes, int n_in,
                              void* d_out, int out_size, void* d_ws, size_t ws_size,
                              hipStream_t stream) {
    const float* x  = (const float*)d_in[0];
    const int* tids = (const int*)d_in[1];
    const float* W1 = (const float*)d_in[2];
    const float* b1 = (const float*)d_in[3];
    const float* W2 = (const float*)d_in[4];
    const float* b2 = (const float*)d_in[5];
    float* out = (float*)d_out;

    dim3 grid(kN / ROWS);   // 512 blocks
    dim3 block(BLK);        // 512 threads
    hipLaunchKernelGGL(tcp_fused, grid, block, 0, stream,
                       x, tids, W1, b1, W2, b2, out);
}